// Round 5
// baseline (337.603 us; speedup 1.0000x reference)
//
#include <hip/hip_runtime.h>
#include <math.h>

// SpaceFillingVQ: N=65536 rows, D=64, E=4096 entries.
// bf16-split (3-term) MFMA distance pass; 32 rows/wave (2 row-groups) to halve
// DS traffic; double-buffered LDS staging; finish folded into main kernel tail;
// exact fp32 rescue (parallel scan) for rows whose gap < TAU.

constexpr int D = 64;
constexpr int CHUNK = 128;          // codebook entries staged in LDS per iteration
constexpr int NTILES = CHUNK / 16;  // 16-entry MFMA tiles per chunk
constexpr int E_PAD = 4096;
constexpr int NCH = E_PAD / CHUNK;  // 32 chunks
constexpr float TAU = 0.01f;        // distance-domain gap threshold for rescue
constexpr int NSLICE = 8;
constexpr int SLICE_E = E_PAD / NSLICE;  // 512 entries per rescue slice
constexpr int BLK = 256;            // 4 waves per block
constexpr int ROWS_PER_BLOCK = 128; // 32 rows per wave

typedef __attribute__((ext_vector_type(8))) short bf16x8;
typedef __attribute__((ext_vector_type(4))) float f32x4;

__device__ inline unsigned short f2bf(float x) {  // round-to-nearest-even bf16
  unsigned int u = __float_as_uint(x);
  u = (u + 0x7fffu + ((u >> 16) & 1u)) >> 16;
  return (unsigned short)u;
}
__device__ inline float bf2f(unsigned short h) {
  return __uint_as_float(((unsigned int)h) << 16);
}

// ---------------- Kernel 1: dithered codebook (f32 + bf16 hi/lo split) + c2/2 ----
__global__ __launch_bounds__(64) void build_kernel(
    const float* __restrict__ cb, const float* __restrict__ dither,
    float* __restrict__ dcb, unsigned short* __restrict__ dcbh,
    unsigned short* __restrict__ dcbl, float* __restrict__ c2h, int E, int Em1) {
  int i = blockIdx.x;
  int k = threadIdx.x;
  if (i >= Em1) {  // pad entries: never selectable
    dcb[(size_t)i * D + k] = 0.f;
    dcbh[(size_t)i * D + k] = 0;
    dcbl[(size_t)i * D + k] = 0;
    if (k == 0) c2h[i] = 3.0e38f;
    return;
  }
  float frac = dither[i] + (float)i;  // replicate reference f32 arithmetic
  int ii = (int)floorf(frac);
  ii = max(0, min(ii, E - 2));
  float r = frac - (float)ii;
  float v = (1.0f - r) * cb[(size_t)ii * D + k] + r * cb[(size_t)(ii + 1) * D + k];
  dcb[(size_t)i * D + k] = v;
  unsigned short h = f2bf(v);
  unsigned short l = f2bf(v - bf2f(h));
  dcbh[(size_t)i * D + k] = h;
  dcbl[(size_t)i * D + k] = l;
  float s = v * v;
#pragma unroll
  for (int off = 32; off > 0; off >>= 1) s += __shfl_down(s, off, 64);
  if (k == 0) c2h[i] = 0.5f * s;
}

// ---------------- Kernel 2: MFMA distance + best/second + finalize ------------
// block = 256 threads = 4 waves; each wave owns 32 rows (2 row-groups of 16).
// maximize s = dot - c2/2; track (b1,i1) and b2; double-buffered LDS staging.
__global__ __launch_bounds__(BLK) void vq_main_kernel(
    const float* __restrict__ X, const unsigned short* __restrict__ dcbh,
    const unsigned short* __restrict__ dcbl, const float* __restrict__ c2h,
    const float* __restrict__ dcb, float* __restrict__ outq,
    float* __restrict__ outidx, float* __restrict__ counts,
    int* __restrict__ rescue_n, int* __restrict__ rescue_list, int N) {
  __shared__ unsigned short s_h[2][CHUNK * D];
  __shared__ unsigned short s_l[2][CHUNK * D];
  __shared__ float s_c2[2][CHUNK];
  __shared__ int s_widx[4][32];
  __shared__ float s_wgap[4][32];

  const int tid = threadIdx.x;
  const int lane = tid & 63;
  const int wv = tid >> 6;
  const int col = lane & 15;   // MFMA col / A-row within 16
  const int kg = lane >> 4;    // k-group 0..3
  const int wvbase = blockIdx.x * ROWS_PER_BLOCK + wv * 32;

  // ---- A fragments for 2 row-groups: bf16 hi/lo, 2 K-halves each
  bf16x8 ah0[2], ah1[2], al0[2], al1[2];
#pragma unroll
  for (int rg = 0; rg < 2; ++rg) {
    const float* xp = X + (size_t)(wvbase + rg * 16 + col) * D + kg * 8;
#pragma unroll
    for (int i = 0; i < 8; ++i) {
      float x0 = xp[i], x1 = xp[32 + i];
      unsigned short h0 = f2bf(x0), h1 = f2bf(x1);
      ah0[rg][i] = (short)h0; ah1[rg][i] = (short)h1;
      al0[rg][i] = (short)f2bf(x0 - bf2f(h0));
      al1[rg][i] = (short)f2bf(x1 - bf2f(h1));
    }
  }

  float b1[2][4], b2[2][4];
  int i1[2][4];
#pragma unroll
  for (int rg = 0; rg < 2; ++rg)
#pragma unroll
    for (int r = 0; r < 4; ++r) { b1[rg][r] = -3.4e38f; b2[rg][r] = -3.4e38f; i1[rg][r] = 0; }

  const int xs = col & 7;  // XOR-swizzle key
  uint4 rh[4], rl[4];
  float rc2 = 0.f;

#define LOADCH(ch)                                                            \
  {                                                                           \
    const int eb_ = (ch) * CHUNK;                                             \
    _Pragma("unroll") for (int k = 0; k < 4; ++k) {                           \
      int u = tid + k * BLK;                                                  \
      int e = u >> 3, g = u & 7;                                              \
      rh[k] = *(const uint4*)(dcbh + (((size_t)(eb_ + e)) << 6) + g * 8);     \
      rl[k] = *(const uint4*)(dcbl + (((size_t)(eb_ + e)) << 6) + g * 8);     \
    }                                                                         \
    if (tid < CHUNK) rc2 = c2h[(ch) * CHUNK + tid];                           \
  }

#define WRITECH(buf)                                                          \
  {                                                                           \
    _Pragma("unroll") for (int k = 0; k < 4; ++k) {                           \
      int u = tid + k * BLK;                                                  \
      int e = u >> 3, g = u & 7;                                              \
      int wa = e * 128 + ((g ^ (e & 7)) << 4);                                \
      *(uint4*)((char*)s_h[buf] + wa) = rh[k];                                \
      *(uint4*)((char*)s_l[buf] + wa) = rl[k];                                \
    }                                                                         \
    if (tid < CHUNK) s_c2[buf][tid] = rc2;                                    \
  }

  LOADCH(0);
  WRITECH(0);
  __syncthreads();
  int cur = 0;

  for (int ch = 0; ch < NCH; ++ch) {
    const int ebase = ch * CHUNK;
    const bool nxt = (ch + 1 < NCH);
    if (nxt) LOADCH(ch + 1);  // issue early: latency hides under MFMA below

#pragma unroll
    for (int t = 0; t < NTILES; ++t) {
      const int el = t * 16 + col;
      const char* bb = (const char*)s_h[cur] + el * 128;
      const char* ll = (const char*)s_l[cur] + el * 128;
      bf16x8 bh0 = *(const bf16x8*)(bb + ((kg ^ xs) << 4));
      bf16x8 bh1 = *(const bf16x8*)(bb + (((kg + 4) ^ xs) << 4));
      bf16x8 bl0 = *(const bf16x8*)(ll + ((kg ^ xs) << 4));
      bf16x8 bl1 = *(const bf16x8*)(ll + (((kg + 4) ^ xs) << 4));
      float hc2 = s_c2[cur][el];
      int colg = ebase + el;
#pragma unroll
      for (int rg = 0; rg < 2; ++rg) {
        f32x4 a0 = {0.f, 0.f, 0.f, 0.f}, a1 = {0.f, 0.f, 0.f, 0.f};
        a0 = __builtin_amdgcn_mfma_f32_16x16x32_bf16(ah0[rg], bh0, a0, 0, 0, 0);
        a1 = __builtin_amdgcn_mfma_f32_16x16x32_bf16(ah1[rg], bh1, a1, 0, 0, 0);
        a0 = __builtin_amdgcn_mfma_f32_16x16x32_bf16(ah0[rg], bl0, a0, 0, 0, 0);
        a1 = __builtin_amdgcn_mfma_f32_16x16x32_bf16(ah1[rg], bl1, a1, 0, 0, 0);
        a0 = __builtin_amdgcn_mfma_f32_16x16x32_bf16(al0[rg], bh0, a0, 0, 0, 0);
        a1 = __builtin_amdgcn_mfma_f32_16x16x32_bf16(al1[rg], bh1, a1, 0, 0, 0);
#pragma unroll
        for (int r = 0; r < 4; ++r) {
          float s = (a0[r] + a1[r]) - hc2;
          bool gt = s > b1[rg][r];                    // strict > -> first occurrence
          b2[rg][r] = fmaxf(b2[rg][r], fminf(s, b1[rg][r]));
          b1[rg][r] = fmaxf(b1[rg][r], s);
          i1[rg][r] = gt ? colg : i1[rg][r];
        }
      }
    }

    if (nxt) WRITECH(cur ^ 1);  // buf[cur^1] free since barrier ending ch-1
    __syncthreads();
    cur ^= 1;
  }

  // cross-lane reduce over 16 cols
#pragma unroll
  for (int m = 1; m < 16; m <<= 1) {
#pragma unroll
    for (int rg = 0; rg < 2; ++rg)
#pragma unroll
      for (int r = 0; r < 4; ++r) {
        float ob1 = __shfl_xor(b1[rg][r], m, 64);
        float ob2 = __shfl_xor(b2[rg][r], m, 64);
        int oi1 = __shfl_xor(i1[rg][r], m, 64);
        float loser = fminf(b1[rg][r], ob1);
        b2[rg][r] = fmaxf(fmaxf(b2[rg][r], ob2), loser);
        bool take = (ob1 > b1[rg][r]) || (ob1 == b1[rg][r] && oi1 < i1[rg][r]);
        b1[rg][r] = take ? ob1 : b1[rg][r];
        i1[rg][r] = take ? oi1 : i1[rg][r];
      }
  }
  if (col == 0) {
#pragma unroll
    for (int rg = 0; rg < 2; ++rg)
#pragma unroll
      for (int r = 0; r < 4; ++r) {
        s_widx[wv][rg * 16 + kg * 4 + r] = i1[rg][r];  // row=(lane>>4)*4+reg map
        s_wgap[wv][rg * 16 + kg * 4 + r] = b1[rg][r] - b2[rg][r];
      }
  }
  __syncthreads();

  // folded finalize: idx write, histogram / rescue flag, coalesced gather write
#pragma unroll 4
  for (int rr = 0; rr < 32; ++rr) {
    const int row = wvbase + rr;
    const int bi = s_widx[wv][rr];
    if (lane == 0) {
      outidx[row] = (float)bi;
      float gap2 = 2.0f * s_wgap[wv][rr];
      if (gap2 < TAU) {
        int p = atomicAdd(rescue_n, 1);
        rescue_list[p] = row;
      } else {
        atomicAdd(&counts[bi], 1.0f);  // exact sums of 1.0f
      }
    }
    outq[(size_t)row * D + lane] = dcb[(size_t)bi * D + lane];
  }
#undef LOADCH
#undef WRITECH
}

// ---------------- Kernel 3a: parallel exact rescue scan -----------------------
__global__ __launch_bounds__(64) void rescue_scan_kernel(
    const float* __restrict__ X, const float* __restrict__ dcb,
    const float* __restrict__ c2h, const int* __restrict__ rescue_n,
    const int* __restrict__ rescue_list,
    float* __restrict__ pd, int* __restrict__ pi) {
  const int lane = threadIdx.x;
  const int nu = (*rescue_n) * NSLICE;
  for (int u = blockIdx.x; u < nu; u += gridDim.x) {
    const int li = u >> 3;
    const int sl = u & (NSLICE - 1);
    const int row = rescue_list[li];

    const float4* xr = (const float4*)(X + (size_t)row * D);
    float4 x[16];
#pragma unroll
    for (int k = 0; k < 16; ++k) x[k] = xr[k];  // wave-uniform broadcast loads

    float best = 3.4e38f;
    int bidx = 0x7fffffff;
    const int e0 = sl * SLICE_E;
#pragma unroll 2
    for (int j = 0; j < SLICE_E / 64; ++j) {
      const int e = e0 + j * 64 + lane;  // ascending per lane -> strict < = first min
      const float4* cp = (const float4*)(dcb + (size_t)e * D);
      float d0 = 0.f, d1 = 0.f, d2 = 0.f, d3 = 0.f;
#pragma unroll
      for (int k = 0; k < 16; ++k) {
        float4 c = cp[k];
        d0 = fmaf(x[k].x, c.x, d0);
        d1 = fmaf(x[k].y, c.y, d1);
        d2 = fmaf(x[k].z, c.z, d2);
        d3 = fmaf(x[k].w, c.w, d3);
      }
      float d = c2h[e] - ((d0 + d1) + (d2 + d3));  // monotone in true distance
      if (d < best) { best = d; bidx = e; }
    }
#pragma unroll
    for (int m = 1; m < 64; m <<= 1) {
      float od = __shfl_xor(best, m, 64);
      int oi = __shfl_xor(bidx, m, 64);
      if (od < best || (od == best && oi < bidx)) { best = od; bidx = oi; }
    }
    if (lane == 0) { pd[u] = best; pi[u] = bidx; }
  }
}

// ---------------- Kernel 3b: rescue finalize ----------------------------------
__global__ __launch_bounds__(64) void rescue_fin_kernel(
    const float* __restrict__ dcb, const int* __restrict__ rescue_n,
    const int* __restrict__ rescue_list, const float* __restrict__ pd,
    const int* __restrict__ pi, float* __restrict__ outq,
    float* __restrict__ outidx, float* __restrict__ counts) {
  const int lane = threadIdx.x;
  const int nr = *rescue_n;
  for (int li = blockIdx.x; li < nr; li += gridDim.x) {
    const int row = rescue_list[li];
    float d = (lane < NSLICE) ? pd[li * NSLICE + lane] : 3.5e38f;
    int ix = (lane < NSLICE) ? pi[li * NSLICE + lane] : 0x7fffffff;
#pragma unroll
    for (int m = 1; m < NSLICE; m <<= 1) {
      float od = __shfl_xor(d, m, 64);
      int oi = __shfl_xor(ix, m, 64);
      if (od < d || (od == d && oi < ix)) { d = od; ix = oi; }
    }
    int bfin = __shfl(ix, 0, 64);
    if (lane == 0) {
      outidx[row] = (float)bfin;
      atomicAdd(&counts[bfin], 1.0f);
    }
    outq[(size_t)row * D + lane] = dcb[(size_t)bfin * D + lane];
  }
}

// ---------------- Kernel 4: perplexity ----------------------------------------
__global__ __launch_bounds__(256) void vq_perp_kernel(
    const float* __restrict__ counts, float* __restrict__ out, int E, float invN) {
  __shared__ float red[4];
  float s = 0.f;
  for (int j = threadIdx.x; j < E; j += 256) {
    float p = counts[j] * invN;
    s += p * logf(p + 1e-10f);
  }
#pragma unroll
  for (int off = 32; off > 0; off >>= 1) s += __shfl_down(s, off, 64);
  int wid = threadIdx.x >> 6;
  if ((threadIdx.x & 63) == 0) red[wid] = s;
  __syncthreads();
  if (threadIdx.x == 0) {
    float t = (red[0] + red[1]) + (red[2] + red[3]);
    out[0] = expf(-t);
  }
}

static inline size_t align256(size_t x) { return (x + 255) & ~(size_t)255; }

extern "C" void kernel_launch(void* const* d_in, const int* in_sizes, int n_in,
                              void* d_out, int out_size, void* d_ws, size_t ws_size,
                              hipStream_t stream) {
  const float* X      = (const float*)d_in[0];
  const float* cb     = (const float*)d_in[1];
  const float* dither = (const float*)d_in[2];

  const int N   = in_sizes[0] / D;  // 65536
  const int E   = in_sizes[1] / D;  // 4096
  const int Em1 = in_sizes[2];      // 4095

  char* w = (char*)d_ws;
  float* dcb            = (float*)w;          w += align256((size_t)E_PAD * D * sizeof(float));
  unsigned short* dcbh  = (unsigned short*)w; w += align256((size_t)E_PAD * D * sizeof(short));
  unsigned short* dcbl  = (unsigned short*)w; w += align256((size_t)E_PAD * D * sizeof(short));
  float* c2h            = (float*)w;          w += align256((size_t)E_PAD * sizeof(float));
  float* counts         = (float*)w;          w += align256((size_t)E_PAD * sizeof(float));
  int* rescue_n         = (int*)w;            w += align256(sizeof(int));
  int* rescue_list      = (int*)w;            w += align256((size_t)N * sizeof(int));
  float* pd             = (float*)w;          w += align256((size_t)N * NSLICE * sizeof(float));
  int* pi               = (int*)w;            w += align256((size_t)N * NSLICE * sizeof(int));

  float* outq   = (float*)d_out;
  float* perp   = (float*)d_out + (size_t)N * D;
  float* outidx = (float*)d_out + (size_t)N * D + 1;

  hipMemsetAsync(counts, 0, (size_t)E_PAD * sizeof(float), stream);
  hipMemsetAsync(rescue_n, 0, sizeof(int), stream);

  build_kernel<<<E_PAD, 64, 0, stream>>>(cb, dither, dcb, dcbh, dcbl, c2h, E, Em1);

  vq_main_kernel<<<N / ROWS_PER_BLOCK, BLK, 0, stream>>>(
      X, dcbh, dcbl, c2h, dcb, outq, outidx, counts, rescue_n, rescue_list, N);

  rescue_scan_kernel<<<2048, 64, 0, stream>>>(X, dcb, c2h, rescue_n, rescue_list, pd, pi);

  rescue_fin_kernel<<<1024, 64, 0, stream>>>(dcb, rescue_n, rescue_list, pd, pi,
                                             outq, outidx, counts);

  vq_perp_kernel<<<1, 256, 0, stream>>>(counts, perp, E, 1.0f / (float)N);
}

// Round 6
// 175.494 us; speedup vs baseline: 1.9237x; 1.9237x over previous
//
#include <hip/hip_runtime.h>
#include <math.h>

// SpaceFillingVQ: N=65536 rows, D=64, E=4096 entries.
// bf16-split (3-term) MFMA distance pass (16 rows/wave, round-4 structure),
// global_load_lds double-buffered staging with pre-swizzled source,
// chained accumulator + med3 second-best. Exact fp32 rescue for gap < TAU.

constexpr int D = 64;
constexpr int CHUNK = 128;          // codebook entries staged in LDS per iteration
constexpr int NTILES = CHUNK / 16;  // 16-entry MFMA tiles per chunk
constexpr int E_PAD = 4096;
constexpr int NCH = E_PAD / CHUNK;  // 32 chunks
constexpr float TAU = 0.01f;        // distance-domain gap threshold for rescue
constexpr int NSLICE = 8;
constexpr int SLICE_E = E_PAD / NSLICE;  // 512 entries per rescue slice

typedef __attribute__((ext_vector_type(8))) short bf16x8;
typedef __attribute__((ext_vector_type(4))) float f32x4;

__device__ inline unsigned short f2bf(float x) {  // round-to-nearest-even bf16
  unsigned int u = __float_as_uint(x);
  u = (u + 0x7fffu + ((u >> 16) & 1u)) >> 16;
  return (unsigned short)u;
}
__device__ inline float bf2f(unsigned short h) {
  return __uint_as_float(((unsigned int)h) << 16);
}

__device__ __forceinline__ void gll16(const void* g, void* l) {
  __builtin_amdgcn_global_load_lds(
      (const __attribute__((address_space(1))) unsigned int*)g,
      (__attribute__((address_space(3))) unsigned int*)l, 16, 0, 0);
}
__device__ __forceinline__ void gll4(const void* g, void* l) {
  __builtin_amdgcn_global_load_lds(
      (const __attribute__((address_space(1))) unsigned int*)g,
      (__attribute__((address_space(3))) unsigned int*)l, 4, 0, 0);
}

// ---------------- Kernel 1: dithered codebook (f32 + bf16 hi/lo split) + c2/2 ----
__global__ __launch_bounds__(64) void build_kernel(
    const float* __restrict__ cb, const float* __restrict__ dither,
    float* __restrict__ dcb, unsigned short* __restrict__ dcbh,
    unsigned short* __restrict__ dcbl, float* __restrict__ c2h, int E, int Em1) {
  int i = blockIdx.x;
  int k = threadIdx.x;
  if (i >= Em1) {  // pad entries: never selectable
    dcb[(size_t)i * D + k] = 0.f;
    dcbh[(size_t)i * D + k] = 0;
    dcbl[(size_t)i * D + k] = 0;
    if (k == 0) c2h[i] = 3.0e38f;
    return;
  }
  float frac = dither[i] + (float)i;  // replicate reference f32 arithmetic
  int ii = (int)floorf(frac);
  ii = max(0, min(ii, E - 2));
  float r = frac - (float)ii;
  float v = (1.0f - r) * cb[(size_t)ii * D + k] + r * cb[(size_t)(ii + 1) * D + k];
  dcb[(size_t)i * D + k] = v;
  unsigned short h = f2bf(v);
  unsigned short l = f2bf(v - bf2f(h));
  dcbh[(size_t)i * D + k] = h;
  dcbl[(size_t)i * D + k] = l;
  float s = v * v;
#pragma unroll
  for (int off = 32; off > 0; off >>= 1) s += __shfl_down(s, off, 64);
  if (k == 0) c2h[i] = 0.5f * s;
}

// ---------------- Kernel 2: MFMA distance + best/second-best per row ----------
// block = 512 threads = 8 waves; each wave owns 16 rows; all E entries scanned.
// maximize s = dot - c2/2; double-buffered global_load_lds staging.
__global__ __launch_bounds__(512) void vq_mfma_kernel(
    const float* __restrict__ X, const unsigned short* __restrict__ dcbh,
    const unsigned short* __restrict__ dcbl, const float* __restrict__ c2h,
    int* __restrict__ out_i1, float* __restrict__ out_gap, int N) {
  __shared__ unsigned short s_h[2][CHUNK * D];
  __shared__ unsigned short s_l[2][CHUNK * D];
  __shared__ float s_c2[2][CHUNK];

  const int tid = threadIdx.x;
  const int lane = tid & 63;
  const int wv = tid >> 6;
  const int col = lane & 15;   // MFMA col / A-row within 16
  const int kg = lane >> 4;    // k-group 0..3
  const int rowbase = blockIdx.x * 128 + wv * 16;

  // ---- A fragments: rows in registers, bf16 hi/lo, 2 K-halves (k 0-31, 32-63)
  const float* xp = X + (size_t)(rowbase + col) * D + kg * 8;
  bf16x8 ah0, ah1, al0, al1;
#pragma unroll
  for (int i = 0; i < 8; ++i) {
    float x0 = xp[i], x1 = xp[32 + i];
    unsigned short h0 = f2bf(x0), h1 = f2bf(x1);
    ah0[i] = (short)h0; ah1[i] = (short)h1;
    al0[i] = (short)f2bf(x0 - bf2f(h0));
    al1[i] = (short)f2bf(x1 - bf2f(h1));
  }

  float b1[4], b2[4];
  int i1[4];
#pragma unroll
  for (int r = 0; r < 4; ++r) { b1[r] = -3.4e38f; b2[r] = -3.4e38f; i1[r] = 0; }

  const int xs = col & 7;  // XOR-swizzle key (entry&7 within tile == col&7)

  // staging: pre-swizzled GLOBAL source + linear LDS dest (rule #21).
  // hi/lo each: 1024 16B-units; wave wv does units [(wv*2+i)*64 + lane].
  auto stage = [&](int ch, int buf) {
#pragma unroll
    for (int i = 0; i < 2; ++i) {
      const int u = (wv * 2 + i) * 64 + lane;
      const int e = u >> 3, g = u & 7;
      const size_t goff = (((size_t)(ch * CHUNK + e)) << 6) + ((g ^ (e & 7)) << 3);
      char* dst_h = (char*)s_h[buf] + (size_t)(wv * 2 + i) * 1024;  // +lane*16 by HW
      char* dst_l = (char*)s_l[buf] + (size_t)(wv * 2 + i) * 1024;
      gll16(dcbh + goff, dst_h);
      gll16(dcbl + goff, dst_l);
    }
    if (wv < 2) {  // wave-uniform branch
      gll4(c2h + ch * CHUNK + wv * 64 + lane, (char*)s_c2[buf] + wv * 256);
    }
  };

  stage(0, 0);
  __syncthreads();  // drains vmcnt -> buf0 valid
  int cur = 0;

  for (int ch = 0; ch < NCH; ++ch) {
    const int ebase = ch * CHUNK;
    if (ch + 1 < NCH) stage(ch + 1, cur ^ 1);  // prefetch hides under MFMA below

#pragma unroll
    for (int t = 0; t < NTILES; ++t) {
      const int el = t * 16 + col;
      const char* bb = (const char*)s_h[cur] + el * 128;
      const char* ll = (const char*)s_l[cur] + el * 128;
      bf16x8 bh0 = *(const bf16x8*)(bb + ((kg ^ xs) << 4));
      bf16x8 bh1 = *(const bf16x8*)(bb + (((kg + 4) ^ xs) << 4));
      bf16x8 bl0 = *(const bf16x8*)(ll + ((kg ^ xs) << 4));
      bf16x8 bl1 = *(const bf16x8*)(ll + (((kg + 4) ^ xs) << 4));
      f32x4 acc = {0.f, 0.f, 0.f, 0.f};  // chained K-loop accumulator
      acc = __builtin_amdgcn_mfma_f32_16x16x32_bf16(ah0, bh0, acc, 0, 0, 0);
      acc = __builtin_amdgcn_mfma_f32_16x16x32_bf16(ah1, bh1, acc, 0, 0, 0);
      acc = __builtin_amdgcn_mfma_f32_16x16x32_bf16(ah0, bl0, acc, 0, 0, 0);
      acc = __builtin_amdgcn_mfma_f32_16x16x32_bf16(ah1, bl1, acc, 0, 0, 0);
      acc = __builtin_amdgcn_mfma_f32_16x16x32_bf16(al0, bh0, acc, 0, 0, 0);
      acc = __builtin_amdgcn_mfma_f32_16x16x32_bf16(al1, bh1, acc, 0, 0, 0);
      float hc2 = s_c2[cur][el];
      int colg = ebase + el;
#pragma unroll
      for (int r = 0; r < 4; ++r) {
        float s = acc[r] - hc2;
        bool gt = s > b1[r];                           // strict > -> first occurrence
        b2[r] = __builtin_amdgcn_fmed3f(b2[r], s, b1[r]);  // = max(b2,min(s,b1)), b2<=b1
        b1[r] = fmaxf(b1[r], s);
        i1[r] = gt ? colg : i1[r];
      }
    }

    __syncthreads();  // drains vmcnt(0): prefetch landed; lgkm: reads done
    cur ^= 1;
  }

  // cross-lane reduce over 16 cols (xor within lane&15; same row group = lane>>4)
#pragma unroll
  for (int m = 1; m < 16; m <<= 1) {
#pragma unroll
    for (int r = 0; r < 4; ++r) {
      float ob1 = __shfl_xor(b1[r], m, 64);
      float ob2 = __shfl_xor(b2[r], m, 64);
      int oi1 = __shfl_xor(i1[r], m, 64);
      float loser = fminf(b1[r], ob1);
      b2[r] = fmaxf(fmaxf(b2[r], ob2), loser);
      bool take = (ob1 > b1[r]) || (ob1 == b1[r] && oi1 < i1[r]);
      b1[r] = take ? ob1 : b1[r];
      i1[r] = take ? oi1 : i1[r];
    }
  }
  if (col == 0) {
#pragma unroll
    for (int r = 0; r < 4; ++r) {
      int row = rowbase + kg * 4 + r;  // row = (lane>>4)*4 + reg (verified C/D map)
      out_i1[row] = i1[r];
      out_gap[row] = b1[r] - b2[r];    // s-domain gap; dist gap = 2x
    }
  }
}

// ---------------- Kernel 3: finalize rows, histogram, quantized gather --------
__global__ __launch_bounds__(64) void finish_kernel(
    const int* __restrict__ out_i1, const float* __restrict__ out_gap,
    const float* __restrict__ dcb, float* __restrict__ outq,
    float* __restrict__ outidx, float* __restrict__ counts,
    int* __restrict__ rescue_n, int* __restrict__ rescue_list, int N) {
  const int lane = threadIdx.x;
  const int rowbase = blockIdx.x * 64;
  const int row = rowbase + lane;
  int bi = out_i1[row];
  float gap2 = 2.0f * out_gap[row];
  outidx[row] = (float)bi;  // tentative for flagged rows; rescue overwrites
  if (gap2 < TAU) {
    int p = atomicAdd(rescue_n, 1);
    rescue_list[p] = row;
  } else {
    atomicAdd(&counts[bi], 1.0f);  // exact sums of 1.0f
  }
  for (int r = 0; r < 64; ++r) {
    int idx_r = __shfl(bi, r, 64);
    outq[(size_t)(rowbase + r) * D + lane] = dcb[(size_t)idx_r * D + lane];
  }
}

// ---------------- Kernel 4a: parallel exact rescue scan -----------------------
__global__ __launch_bounds__(64) void rescue_scan_kernel(
    const float* __restrict__ X, const float* __restrict__ dcb,
    const float* __restrict__ c2h, const int* __restrict__ rescue_n,
    const int* __restrict__ rescue_list,
    float* __restrict__ pd, int* __restrict__ pi) {
  const int lane = threadIdx.x;
  const int nu = (*rescue_n) * NSLICE;
  for (int u = blockIdx.x; u < nu; u += gridDim.x) {
    const int li = u >> 3;
    const int sl = u & (NSLICE - 1);
    const int row = rescue_list[li];

    const float4* xr = (const float4*)(X + (size_t)row * D);
    float4 x[16];
#pragma unroll
    for (int k = 0; k < 16; ++k) x[k] = xr[k];  // wave-uniform broadcast loads

    float best = 3.4e38f;
    int bidx = 0x7fffffff;
    const int e0 = sl * SLICE_E;
#pragma unroll 2
    for (int j = 0; j < SLICE_E / 64; ++j) {
      const int e = e0 + j * 64 + lane;  // ascending per lane -> strict < = first min
      const float4* cp = (const float4*)(dcb + (size_t)e * D);
      float d0 = 0.f, d1 = 0.f, d2 = 0.f, d3 = 0.f;
#pragma unroll
      for (int k = 0; k < 16; ++k) {
        float4 c = cp[k];
        d0 = fmaf(x[k].x, c.x, d0);
        d1 = fmaf(x[k].y, c.y, d1);
        d2 = fmaf(x[k].z, c.z, d2);
        d3 = fmaf(x[k].w, c.w, d3);
      }
      float d = c2h[e] - ((d0 + d1) + (d2 + d3));  // monotone in true distance
      if (d < best) { best = d; bidx = e; }
    }
#pragma unroll
    for (int m = 1; m < 64; m <<= 1) {
      float od = __shfl_xor(best, m, 64);
      int oi = __shfl_xor(bidx, m, 64);
      if (od < best || (od == best && oi < bidx)) { best = od; bidx = oi; }
    }
    if (lane == 0) { pd[u] = best; pi[u] = bidx; }
  }
}

// ---------------- Kernel 4b: rescue finalize ----------------------------------
__global__ __launch_bounds__(64) void rescue_fin_kernel(
    const float* __restrict__ dcb, const int* __restrict__ rescue_n,
    const int* __restrict__ rescue_list, const float* __restrict__ pd,
    const int* __restrict__ pi, float* __restrict__ outq,
    float* __restrict__ outidx, float* __restrict__ counts) {
  const int lane = threadIdx.x;
  const int nr = *rescue_n;
  for (int li = blockIdx.x; li < nr; li += gridDim.x) {
    const int row = rescue_list[li];
    float d = (lane < NSLICE) ? pd[li * NSLICE + lane] : 3.5e38f;
    int ix = (lane < NSLICE) ? pi[li * NSLICE + lane] : 0x7fffffff;
#pragma unroll
    for (int m = 1; m < NSLICE; m <<= 1) {
      float od = __shfl_xor(d, m, 64);
      int oi = __shfl_xor(ix, m, 64);
      if (od < d || (od == d && oi < ix)) { d = od; ix = oi; }
    }
    int bfin = __shfl(ix, 0, 64);
    if (lane == 0) {
      outidx[row] = (float)bfin;
      atomicAdd(&counts[bfin], 1.0f);
    }
    outq[(size_t)row * D + lane] = dcb[(size_t)bfin * D + lane];
  }
}

// ---------------- Kernel 5: perplexity ----------------------------------------
__global__ __launch_bounds__(256) void vq_perp_kernel(
    const float* __restrict__ counts, float* __restrict__ out, int E, float invN) {
  __shared__ float red[4];
  float s = 0.f;
  for (int j = threadIdx.x; j < E; j += 256) {
    float p = counts[j] * invN;
    s += p * logf(p + 1e-10f);
  }
#pragma unroll
  for (int off = 32; off > 0; off >>= 1) s += __shfl_down(s, off, 64);
  int wid = threadIdx.x >> 6;
  if ((threadIdx.x & 63) == 0) red[wid] = s;
  __syncthreads();
  if (threadIdx.x == 0) {
    float t = (red[0] + red[1]) + (red[2] + red[3]);
    out[0] = expf(-t);
  }
}

static inline size_t align256(size_t x) { return (x + 255) & ~(size_t)255; }

extern "C" void kernel_launch(void* const* d_in, const int* in_sizes, int n_in,
                              void* d_out, int out_size, void* d_ws, size_t ws_size,
                              hipStream_t stream) {
  const float* X      = (const float*)d_in[0];
  const float* cb     = (const float*)d_in[1];
  const float* dither = (const float*)d_in[2];

  const int N   = in_sizes[0] / D;  // 65536
  const int E   = in_sizes[1] / D;  // 4096
  const int Em1 = in_sizes[2];      // 4095

  char* w = (char*)d_ws;
  float* dcb            = (float*)w;          w += align256((size_t)E_PAD * D * sizeof(float));
  unsigned short* dcbh  = (unsigned short*)w; w += align256((size_t)E_PAD * D * sizeof(short));
  unsigned short* dcbl  = (unsigned short*)w; w += align256((size_t)E_PAD * D * sizeof(short));
  float* c2h            = (float*)w;          w += align256((size_t)E_PAD * sizeof(float));
  int* out_i1           = (int*)w;            w += align256((size_t)N * sizeof(int));
  float* out_gap        = (float*)w;          w += align256((size_t)N * sizeof(float));
  float* counts         = (float*)w;          w += align256((size_t)E_PAD * sizeof(float));
  int* rescue_n         = (int*)w;            w += align256(sizeof(int));
  int* rescue_list      = (int*)w;            w += align256((size_t)N * sizeof(int));
  float* pd             = (float*)w;          w += align256((size_t)N * NSLICE * sizeof(float));
  int* pi               = (int*)w;            w += align256((size_t)N * NSLICE * sizeof(int));

  float* outq   = (float*)d_out;
  float* perp   = (float*)d_out + (size_t)N * D;
  float* outidx = (float*)d_out + (size_t)N * D + 1;

  hipMemsetAsync(counts, 0, (size_t)E_PAD * sizeof(float), stream);
  hipMemsetAsync(rescue_n, 0, sizeof(int), stream);

  build_kernel<<<E_PAD, 64, 0, stream>>>(cb, dither, dcb, dcbh, dcbl, c2h, E, Em1);

  vq_mfma_kernel<<<N / 128, 512, 0, stream>>>(X, dcbh, dcbl, c2h, out_i1, out_gap, N);

  finish_kernel<<<N / 64, 64, 0, stream>>>(out_i1, out_gap, dcb, outq, outidx, counts,
                                           rescue_n, rescue_list, N);

  rescue_scan_kernel<<<2048, 64, 0, stream>>>(X, dcb, c2h, rescue_n, rescue_list, pd, pi);

  rescue_fin_kernel<<<1024, 64, 0, stream>>>(dcb, rescue_n, rescue_list, pd, pi,
                                             outq, outidx, counts);

  vq_perp_kernel<<<1, 256, 0, stream>>>(counts, perp, E, 1.0f / (float)N);
}

// Round 7
// 173.097 us; speedup vs baseline: 1.9504x; 1.0138x over previous
//
#include <hip/hip_runtime.h>
#include <math.h>

// SpaceFillingVQ: N=65536 rows, D=64, E=4096 entries.
// bf16-split (3-term) MFMA distance pass, 32 rows/wave (2 row-groups sharing
// each B-fragment ds_read -> DS-read per MFMA halved vs round 6),
// global_load_lds double-buffered staging with pre-swizzled source,
// chained accumulator + med3 second-best. Exact fp32 rescue for gap < TAU.

constexpr int D = 64;
constexpr int CHUNK = 128;          // codebook entries staged in LDS per iteration
constexpr int NTILES = CHUNK / 16;  // 16-entry MFMA tiles per chunk
constexpr int E_PAD = 4096;
constexpr int NCH = E_PAD / CHUNK;  // 32 chunks
constexpr float TAU = 0.01f;        // distance-domain gap threshold for rescue
constexpr int NSLICE = 8;
constexpr int SLICE_E = E_PAD / NSLICE;  // 512 entries per rescue slice
constexpr int BLK = 256;            // 4 waves; each wave owns 32 rows

typedef __attribute__((ext_vector_type(8))) short bf16x8;
typedef __attribute__((ext_vector_type(4))) float f32x4;

__device__ inline unsigned short f2bf(float x) {  // round-to-nearest-even bf16
  unsigned int u = __float_as_uint(x);
  u = (u + 0x7fffu + ((u >> 16) & 1u)) >> 16;
  return (unsigned short)u;
}
__device__ inline float bf2f(unsigned short h) {
  return __uint_as_float(((unsigned int)h) << 16);
}

__device__ __forceinline__ void gll16(const void* g, void* l) {
  __builtin_amdgcn_global_load_lds(
      (const __attribute__((address_space(1))) unsigned int*)g,
      (__attribute__((address_space(3))) unsigned int*)l, 16, 0, 0);
}
__device__ __forceinline__ void gll4(const void* g, void* l) {
  __builtin_amdgcn_global_load_lds(
      (const __attribute__((address_space(1))) unsigned int*)g,
      (__attribute__((address_space(3))) unsigned int*)l, 4, 0, 0);
}

// ---------------- Kernel 1: dithered codebook (f32 + bf16 hi/lo split) + c2/2 ----
__global__ __launch_bounds__(64) void build_kernel(
    const float* __restrict__ cb, const float* __restrict__ dither,
    float* __restrict__ dcb, unsigned short* __restrict__ dcbh,
    unsigned short* __restrict__ dcbl, float* __restrict__ c2h, int E, int Em1) {
  int i = blockIdx.x;
  int k = threadIdx.x;
  if (i >= Em1) {  // pad entries: never selectable
    dcb[(size_t)i * D + k] = 0.f;
    dcbh[(size_t)i * D + k] = 0;
    dcbl[(size_t)i * D + k] = 0;
    if (k == 0) c2h[i] = 3.0e38f;
    return;
  }
  float frac = dither[i] + (float)i;  // replicate reference f32 arithmetic
  int ii = (int)floorf(frac);
  ii = max(0, min(ii, E - 2));
  float r = frac - (float)ii;
  float v = (1.0f - r) * cb[(size_t)ii * D + k] + r * cb[(size_t)(ii + 1) * D + k];
  dcb[(size_t)i * D + k] = v;
  unsigned short h = f2bf(v);
  unsigned short l = f2bf(v - bf2f(h));
  dcbh[(size_t)i * D + k] = h;
  dcbl[(size_t)i * D + k] = l;
  float s = v * v;
#pragma unroll
  for (int off = 32; off > 0; off >>= 1) s += __shfl_down(s, off, 64);
  if (k == 0) c2h[i] = 0.5f * s;
}

// ---------------- Kernel 2: MFMA distance + best/second-best per row ----------
// block = 256 threads = 4 waves; each wave owns 32 rows (2 row-groups of 16);
// every B-fragment ds_read feeds 12 MFMA. Double-buffered global_load_lds.
__global__ __launch_bounds__(BLK, 2) void vq_mfma_kernel(
    const float* __restrict__ X, const unsigned short* __restrict__ dcbh,
    const unsigned short* __restrict__ dcbl, const float* __restrict__ c2h,
    int* __restrict__ out_i1, float* __restrict__ out_gap, int N) {
  __shared__ unsigned short s_h[2][CHUNK * D];
  __shared__ unsigned short s_l[2][CHUNK * D];
  __shared__ float s_c2[2][CHUNK];

  const int tid = threadIdx.x;
  const int lane = tid & 63;
  const int wv = tid >> 6;
  const int col = lane & 15;   // MFMA col / A-row within 16
  const int kg = lane >> 4;    // k-group 0..3
  const int wvbase = blockIdx.x * 128 + wv * 32;

  // ---- A fragments for 2 row-groups: bf16 hi/lo, 2 K-halves (k 0-31, 32-63)
  bf16x8 ah0[2], ah1[2], al0[2], al1[2];
#pragma unroll
  for (int rg = 0; rg < 2; ++rg) {
    const float* xp = X + (size_t)(wvbase + rg * 16 + col) * D + kg * 8;
#pragma unroll
    for (int i = 0; i < 8; ++i) {
      float x0 = xp[i], x1 = xp[32 + i];
      unsigned short h0 = f2bf(x0), h1 = f2bf(x1);
      ah0[rg][i] = (short)h0; ah1[rg][i] = (short)h1;
      al0[rg][i] = (short)f2bf(x0 - bf2f(h0));
      al1[rg][i] = (short)f2bf(x1 - bf2f(h1));
    }
  }

  float b1[2][4], b2[2][4];
  int i1[2][4];
#pragma unroll
  for (int rg = 0; rg < 2; ++rg)
#pragma unroll
    for (int r = 0; r < 4; ++r) { b1[rg][r] = -3.4e38f; b2[rg][r] = -3.4e38f; i1[rg][r] = 0; }

  const int xs = col & 7;  // XOR-swizzle key (entry&7 within tile == col&7)

  // staging: pre-swizzled GLOBAL source + linear LDS dest (rule #21).
  // hi/lo each: 1024 16B-units; wave wv does units [(wv*4+i)*64 + lane].
  auto stage = [&](int ch, int buf) {
#pragma unroll
    for (int i = 0; i < 4; ++i) {
      const int u = (wv * 4 + i) * 64 + lane;
      const int e = u >> 3, g = u & 7;
      const size_t goff = (((size_t)(ch * CHUNK + e)) << 6) + ((g ^ (e & 7)) << 3);
      char* dst_h = (char*)s_h[buf] + (size_t)(wv * 4 + i) * 1024;  // +lane*16 by HW
      char* dst_l = (char*)s_l[buf] + (size_t)(wv * 4 + i) * 1024;
      gll16(dcbh + goff, dst_h);
      gll16(dcbl + goff, dst_l);
    }
    if (wv < 2) {  // wave-uniform branch
      gll4(c2h + ch * CHUNK + wv * 64 + lane, (char*)s_c2[buf] + wv * 256);
    }
  };

  stage(0, 0);
  __syncthreads();  // drains vmcnt -> buf0 valid
  int cur = 0;

  for (int ch = 0; ch < NCH; ++ch) {
    const int ebase = ch * CHUNK;
    if (ch + 1 < NCH) stage(ch + 1, cur ^ 1);  // prefetch hides under MFMA below

#pragma unroll
    for (int t = 0; t < NTILES; ++t) {
      const int el = t * 16 + col;
      const char* bb = (const char*)s_h[cur] + el * 128;
      const char* ll = (const char*)s_l[cur] + el * 128;
      bf16x8 bh0 = *(const bf16x8*)(bb + ((kg ^ xs) << 4));
      bf16x8 bh1 = *(const bf16x8*)(bb + (((kg + 4) ^ xs) << 4));
      bf16x8 bl0 = *(const bf16x8*)(ll + ((kg ^ xs) << 4));
      bf16x8 bl1 = *(const bf16x8*)(ll + (((kg + 4) ^ xs) << 4));
      float hc2 = s_c2[cur][el];
      int colg = ebase + el;
#pragma unroll
      for (int rg = 0; rg < 2; ++rg) {
        f32x4 acc = {0.f, 0.f, 0.f, 0.f};  // chained K-loop accumulator
        acc = __builtin_amdgcn_mfma_f32_16x16x32_bf16(ah0[rg], bh0, acc, 0, 0, 0);
        acc = __builtin_amdgcn_mfma_f32_16x16x32_bf16(ah1[rg], bh1, acc, 0, 0, 0);
        acc = __builtin_amdgcn_mfma_f32_16x16x32_bf16(ah0[rg], bl0, acc, 0, 0, 0);
        acc = __builtin_amdgcn_mfma_f32_16x16x32_bf16(ah1[rg], bl1, acc, 0, 0, 0);
        acc = __builtin_amdgcn_mfma_f32_16x16x32_bf16(al0[rg], bh0, acc, 0, 0, 0);
        acc = __builtin_amdgcn_mfma_f32_16x16x32_bf16(al1[rg], bh1, acc, 0, 0, 0);
#pragma unroll
        for (int r = 0; r < 4; ++r) {
          float s = acc[r] - hc2;
          bool gt = s > b1[rg][r];  // strict > -> first occurrence
          b2[rg][r] = __builtin_amdgcn_fmed3f(b2[rg][r], s, b1[rg][r]);  // b2<=b1
          b1[rg][r] = fmaxf(b1[rg][r], s);
          i1[rg][r] = gt ? colg : i1[rg][r];
        }
      }
    }

    __syncthreads();  // drains vmcnt(0): prefetch landed; lgkm: reads done
    cur ^= 1;
  }

  // cross-lane reduce over 16 cols (xor within lane&15; same row group = lane>>4)
#pragma unroll
  for (int m = 1; m < 16; m <<= 1) {
#pragma unroll
    for (int rg = 0; rg < 2; ++rg)
#pragma unroll
      for (int r = 0; r < 4; ++r) {
        float ob1 = __shfl_xor(b1[rg][r], m, 64);
        float ob2 = __shfl_xor(b2[rg][r], m, 64);
        int oi1 = __shfl_xor(i1[rg][r], m, 64);
        float loser = fminf(b1[rg][r], ob1);
        b2[rg][r] = fmaxf(fmaxf(b2[rg][r], ob2), loser);
        bool take = (ob1 > b1[rg][r]) || (ob1 == b1[rg][r] && oi1 < i1[rg][r]);
        b1[rg][r] = take ? ob1 : b1[rg][r];
        i1[rg][r] = take ? oi1 : i1[rg][r];
      }
  }
  if (col == 0) {
#pragma unroll
    for (int rg = 0; rg < 2; ++rg)
#pragma unroll
      for (int r = 0; r < 4; ++r) {
        int row = wvbase + rg * 16 + kg * 4 + r;  // row=(lane>>4)*4+reg (C/D map)
        out_i1[row] = i1[rg][r];
        out_gap[row] = b1[rg][r] - b2[rg][r];     // s-domain gap; dist gap = 2x
      }
  }
}

// ---------------- Kernel 3: finalize rows, histogram, quantized gather --------
__global__ __launch_bounds__(64) void finish_kernel(
    const int* __restrict__ out_i1, const float* __restrict__ out_gap,
    const float* __restrict__ dcb, float* __restrict__ outq,
    float* __restrict__ outidx, float* __restrict__ counts,
    int* __restrict__ rescue_n, int* __restrict__ rescue_list, int N) {
  const int lane = threadIdx.x;
  const int rowbase = blockIdx.x * 64;
  const int row = rowbase + lane;
  int bi = out_i1[row];
  float gap2 = 2.0f * out_gap[row];
  outidx[row] = (float)bi;  // tentative for flagged rows; rescue overwrites
  if (gap2 < TAU) {
    int p = atomicAdd(rescue_n, 1);
    rescue_list[p] = row;
  } else {
    atomicAdd(&counts[bi], 1.0f);  // exact sums of 1.0f
  }
  for (int r = 0; r < 64; ++r) {
    int idx_r = __shfl(bi, r, 64);
    outq[(size_t)(rowbase + r) * D + lane] = dcb[(size_t)idx_r * D + lane];
  }
}

// ---------------- Kernel 4a: parallel exact rescue scan -----------------------
__global__ __launch_bounds__(64) void rescue_scan_kernel(
    const float* __restrict__ X, const float* __restrict__ dcb,
    const float* __restrict__ c2h, const int* __restrict__ rescue_n,
    const int* __restrict__ rescue_list,
    float* __restrict__ pd, int* __restrict__ pi) {
  const int lane = threadIdx.x;
  const int nu = (*rescue_n) * NSLICE;
  for (int u = blockIdx.x; u < nu; u += gridDim.x) {
    const int li = u >> 3;
    const int sl = u & (NSLICE - 1);
    const int row = rescue_list[li];

    const float4* xr = (const float4*)(X + (size_t)row * D);
    float4 x[16];
#pragma unroll
    for (int k = 0; k < 16; ++k) x[k] = xr[k];  // wave-uniform broadcast loads

    float best = 3.4e38f;
    int bidx = 0x7fffffff;
    const int e0 = sl * SLICE_E;
#pragma unroll 2
    for (int j = 0; j < SLICE_E / 64; ++j) {
      const int e = e0 + j * 64 + lane;  // ascending per lane -> strict < = first min
      const float4* cp = (const float4*)(dcb + (size_t)e * D);
      float d0 = 0.f, d1 = 0.f, d2 = 0.f, d3 = 0.f;
#pragma unroll
      for (int k = 0; k < 16; ++k) {
        float4 c = cp[k];
        d0 = fmaf(x[k].x, c.x, d0);
        d1 = fmaf(x[k].y, c.y, d1);
        d2 = fmaf(x[k].z, c.z, d2);
        d3 = fmaf(x[k].w, c.w, d3);
      }
      float d = c2h[e] - ((d0 + d1) + (d2 + d3));  // monotone in true distance
      if (d < best) { best = d; bidx = e; }
    }
#pragma unroll
    for (int m = 1; m < 64; m <<= 1) {
      float od = __shfl_xor(best, m, 64);
      int oi = __shfl_xor(bidx, m, 64);
      if (od < best || (od == best && oi < bidx)) { best = od; bidx = oi; }
    }
    if (lane == 0) { pd[u] = best; pi[u] = bidx; }
  }
}

// ---------------- Kernel 4b: rescue finalize ----------------------------------
__global__ __launch_bounds__(64) void rescue_fin_kernel(
    const float* __restrict__ dcb, const int* __restrict__ rescue_n,
    const int* __restrict__ rescue_list, const float* __restrict__ pd,
    const int* __restrict__ pi, float* __restrict__ outq,
    float* __restrict__ outidx, float* __restrict__ counts) {
  const int lane = threadIdx.x;
  const int nr = *rescue_n;
  for (int li = blockIdx.x; li < nr; li += gridDim.x) {
    const int row = rescue_list[li];
    float d = (lane < NSLICE) ? pd[li * NSLICE + lane] : 3.5e38f;
    int ix = (lane < NSLICE) ? pi[li * NSLICE + lane] : 0x7fffffff;
#pragma unroll
    for (int m = 1; m < NSLICE; m <<= 1) {
      float od = __shfl_xor(d, m, 64);
      int oi = __shfl_xor(ix, m, 64);
      if (od < d || (od == d && oi < ix)) { d = od; ix = oi; }
    }
    int bfin = __shfl(ix, 0, 64);
    if (lane == 0) {
      outidx[row] = (float)bfin;
      atomicAdd(&counts[bfin], 1.0f);
    }
    outq[(size_t)row * D + lane] = dcb[(size_t)bfin * D + lane];
  }
}

// ---------------- Kernel 5: perplexity ----------------------------------------
__global__ __launch_bounds__(256) void vq_perp_kernel(
    const float* __restrict__ counts, float* __restrict__ out, int E, float invN) {
  __shared__ float red[4];
  float s = 0.f;
  for (int j = threadIdx.x; j < E; j += 256) {
    float p = counts[j] * invN;
    s += p * logf(p + 1e-10f);
  }
#pragma unroll
  for (int off = 32; off > 0; off >>= 1) s += __shfl_down(s, off, 64);
  int wid = threadIdx.x >> 6;
  if ((threadIdx.x & 63) == 0) red[wid] = s;
  __syncthreads();
  if (threadIdx.x == 0) {
    float t = (red[0] + red[1]) + (red[2] + red[3]);
    out[0] = expf(-t);
  }
}

static inline size_t align256(size_t x) { return (x + 255) & ~(size_t)255; }

extern "C" void kernel_launch(void* const* d_in, const int* in_sizes, int n_in,
                              void* d_out, int out_size, void* d_ws, size_t ws_size,
                              hipStream_t stream) {
  const float* X      = (const float*)d_in[0];
  const float* cb     = (const float*)d_in[1];
  const float* dither = (const float*)d_in[2];

  const int N   = in_sizes[0] / D;  // 65536
  const int E   = in_sizes[1] / D;  // 4096
  const int Em1 = in_sizes[2];      // 4095

  char* w = (char*)d_ws;
  float* dcb            = (float*)w;          w += align256((size_t)E_PAD * D * sizeof(float));
  unsigned short* dcbh  = (unsigned short*)w; w += align256((size_t)E_PAD * D * sizeof(short));
  unsigned short* dcbl  = (unsigned short*)w; w += align256((size_t)E_PAD * D * sizeof(short));
  float* c2h            = (float*)w;          w += align256((size_t)E_PAD * sizeof(float));
  int* out_i1           = (int*)w;            w += align256((size_t)N * sizeof(int));
  float* out_gap        = (float*)w;          w += align256((size_t)N * sizeof(float));
  float* counts         = (float*)w;          w += align256((size_t)E_PAD * sizeof(float));
  int* rescue_n         = (int*)w;            w += align256(sizeof(int));
  int* rescue_list      = (int*)w;            w += align256((size_t)N * sizeof(int));
  float* pd             = (float*)w;          w += align256((size_t)N * NSLICE * sizeof(float));
  int* pi               = (int*)w;            w += align256((size_t)N * NSLICE * sizeof(int));

  float* outq   = (float*)d_out;
  float* perp   = (float*)d_out + (size_t)N * D;
  float* outidx = (float*)d_out + (size_t)N * D + 1;

  hipMemsetAsync(counts, 0, (size_t)E_PAD * sizeof(float), stream);
  hipMemsetAsync(rescue_n, 0, sizeof(int), stream);

  build_kernel<<<E_PAD, 64, 0, stream>>>(cb, dither, dcb, dcbh, dcbl, c2h, E, Em1);

  vq_mfma_kernel<<<N / 128, BLK, 0, stream>>>(X, dcbh, dcbl, c2h, out_i1, out_gap, N);

  finish_kernel<<<N / 64, 64, 0, stream>>>(out_i1, out_gap, dcb, outq, outidx, counts,
                                           rescue_n, rescue_list, N);

  rescue_scan_kernel<<<2048, 64, 0, stream>>>(X, dcb, c2h, rescue_n, rescue_list, pd, pi);

  rescue_fin_kernel<<<1024, 64, 0, stream>>>(dcb, rescue_n, rescue_list, pd, pi,
                                             outq, outidx, counts);

  vq_perp_kernel<<<1, 256, 0, stream>>>(counts, perp, E, 1.0f / (float)N);
}